// Round 6
// baseline (465.121 us; speedup 1.0000x reference)
//
#include <hip/hip_runtime.h>
#include <hip/hip_bf16.h>

#define NE 32000
#define NNODES 1600
#define CCH 128
#define M0C 7
#define NSPH 49
#define NALLC 29
#define BASIS 512
#define DIN 768
#define HID 128
#define RESCALE_F 23.395238876342773f
#define CH 28                      // edges per rotate chunk
#define MAXCH (NE / CH + NNODES)   // 2743 upper bound on chunk count
#define WCROW 8                    // shorts per compact wigner row (7 + pad)
#define WCPE (NSPH * WCROW)        // 392 shorts per edge in Wc
#define WC_OFF 82558976ull
#define WC_BYTES (2ull * NE * WCPE)

typedef __bf16 bf16x8 __attribute__((ext_vector_type(8)));
typedef __bf16 bf16x2 __attribute__((ext_vector_type(2)));
typedef float  f32x4  __attribute__((ext_vector_type(4)));

__device__ __forceinline__ unsigned short f_to_bf16(float f) {
    unsigned int u = __float_as_uint(f);
    unsigned int r = (u + 0x7FFFu + ((u >> 16) & 1u)) >> 16;
    return (unsigned short)r;
}
__device__ __forceinline__ float silu_f(float x) {
    return x / (1.0f + __expf(-x));
}

// ---------------- prepack weights: FRAGMENT-LINEAR layout (1 KB contiguous
// per (kstep,tile) wave-fragment; lane L's 8 values at [lane*8..lane*8+8)).
__global__ __launch_bounds__(256) void prepack_w(
    const float* __restrict__ w1, const float* __restrict__ w2, const float* __restrict__ w3,
    unsigned short* __restrict__ w1p,  // [24][8][512]
    unsigned short* __restrict__ w2p,  // [4][8][512]
    unsigned short* __restrict__ w3p)  // [4][7][8][512]
{
    int idx = blockIdx.x * 256 + threadIdx.x;
    if (idx < 98304) {                       // w1p: 24*8*512
        int kstep = idx >> 12;
        int ct    = (idx >> 9) & 7;
        int li    = idx & 511;
        int lane = li >> 3, j = li & 7;
        int m = lane & 15, quad = lane >> 4;
        int k = kstep * 32 + quad * 8 + j;
        int n = ct * 16 + m;
        w1p[idx] = f_to_bf16(w1[(size_t)k * 128 + n]);
    } else if (idx < 114688) {               // w2p: 4*8*512
        int j2 = idx - 98304;
        int kstep = j2 >> 12;
        int ct    = (j2 >> 9) & 7;
        int li    = j2 & 511;
        int lane = li >> 3, j = li & 7;
        int m = lane & 15, quad = lane >> 4;
        int k = kstep * 32 + quad * 8 + j;
        int n = ct * 16 + m;
        w2p[j2] = f_to_bf16(w2[(size_t)k * 128 + n]);
    } else if (idx < 229376) {               // w3p: 4*7*8*512
        int j3 = idx - 114688;
        int kstep = j3 / 28672;
        int r     = j3 - kstep * 28672;
        int o     = r >> 12;
        int ctile = (r >> 9) & 7;
        int li    = r & 511;
        int lane = li >> 3, j = li & 7;
        int m = lane & 15, quad = lane >> 4;
        int k = kstep * 32 + quad * 8 + j;
        int n = o * 128 + ctile * 16 + m;
        w3p[j3] = f_to_bf16(w3[(size_t)k * 896 + n]);
    }
}

// ---------------- GEMM1: A-tile (64 rows x 512 dist cols) staged via LDS.
// Stage: fully coalesced float4 loads + bf16 cvt + XOR-swizzled ds_write
// (kills the 16-scattered-line A-load pattern: 50% line use, TA-serialized).
// Swizzle: 8-col group g of row r stored at g ^ (r&7)  -> uniform 8 lanes
// per bank-slot on ds_read_b128 (the 1 KB/instr LDS floor, no extra conflict).
__global__ __launch_bounds__(256) void gemm1_ln_mfma(
    const float* __restrict__ dist,         // [NE,512]
    const int* __restrict__ edge_index,     // [2,NE]
    const int* __restrict__ atomic_numbers, // [NNODES]
    const float* __restrict__ src_table,    // [90,128]
    const float* __restrict__ tgt_table,    // [90,128]
    const unsigned short* __restrict__ w1p, // [24][8][512] fragment-linear
    const float* __restrict__ bias,
    const float* __restrict__ gam,
    const float* __restrict__ bet,
    unsigned short* __restrict__ Out)       // [NE,128] bf16
{
    __shared__ unsigned short Ad[64][512];  // 64 KB

    const int t = threadIdx.x;
    const int wv = t >> 6, lane = t & 63;
    const int m = lane & 15, quad = lane >> 4;
    const int row0 = blockIdx.x * 64;

    // ---- stage 64 rows of dist, coalesced
    {
        const float4* src = (const float4*)(dist + (size_t)row0 * 512);
#pragma unroll 8
        for (int it = 0; it < 32; ++it) {
            int u = it * 256 + t;              // float4 index 0..8191
            float4 v = src[u];
            int row = u >> 7;                  // 0..63
            int c4  = (u & 127) * 4;           // col (floats)
            int gs  = (c4 >> 3) ^ (row & 7);   // swizzled 8-col group
            unsigned short* d = &Ad[row][gs * 8 + (c4 & 7)];
            d[0] = f_to_bf16(v.x); d[1] = f_to_bf16(v.y);
            d[2] = f_to_bf16(v.z); d[3] = f_to_bf16(v.w);
        }
    }

    const int arow = wv * 16 + m;
    const int row  = row0 + arow;
    const int sid  = atomic_numbers[edge_index[row]];
    const int tid2 = atomic_numbers[edge_index[NE + row]];
    const float* a1 = src_table + sid * 128 + quad * 8;
    const float* a2 = tgt_table + tid2 * 128 + quad * 8;
    const unsigned short* bb = w1p + lane * 8;
    __syncthreads();

    f32x4 acc[8] = {};

#pragma unroll
    for (int k0 = 0; k0 < 768; k0 += 32) {
        bf16x8 af;
        if (k0 < 512) {
            int gs = ((k0 >> 3) + quad) ^ (arow & 7);
            af = *(const bf16x8*)&Ad[arow][gs * 8];
        } else {
            const float* ap = (k0 < 640) ? (a1 + (k0 - 512)) : (a2 + (k0 - 640));
            float4 va = *(const float4*)ap;
            float4 vb = *(const float4*)(ap + 4);
            af[0] = (__bf16)va.x; af[1] = (__bf16)va.y;
            af[2] = (__bf16)va.z; af[3] = (__bf16)va.w;
            af[4] = (__bf16)vb.x; af[5] = (__bf16)vb.y;
            af[6] = (__bf16)vb.z; af[7] = (__bf16)vb.w;
        }
#pragma unroll
        for (int ct = 0; ct < 8; ++ct) {
            bf16x8 bfv = *(const bf16x8*)(bb + (size_t)(((k0 >> 5) * 8 + ct)) * 512);
            acc[ct] = __builtin_amdgcn_mfma_f32_16x16x32_bf16(af, bfv, acc[ct], 0, 0, 0);
        }
    }

    float bbv[8], ggv[8], eev[8];
#pragma unroll
    for (int ct = 0; ct < 8; ++ct) {
        bbv[ct] = bias[ct * 16 + m];
        ggv[ct] = gam[ct * 16 + m];
        eev[ct] = bet[ct * 16 + m];
    }
#pragma unroll
    for (int reg = 0; reg < 4; ++reg) {
        float v[8];
        float s = 0.f, s2 = 0.f;
#pragma unroll
        for (int ct = 0; ct < 8; ++ct) {
            v[ct] = acc[ct][reg] + bbv[ct];
            s += v[ct]; s2 += v[ct] * v[ct];
        }
#pragma unroll
        for (int off = 1; off < 16; off <<= 1) {
            s  += __shfl_xor(s, off, 64);
            s2 += __shfl_xor(s2, off, 64);
        }
        float mean = s * (1.0f / 128.0f);
        float var  = s2 * (1.0f / 128.0f) - mean * mean;
        float rstd = rsqrtf(var + 1e-5f);
        int orow = row0 + wv * 16 + 4 * quad + reg;
#pragma unroll
        for (int ct = 0; ct < 8; ++ct) {
            float o = silu_f((v[ct] - mean) * rstd * ggv[ct] + eev[ct]);
            Out[(size_t)orow * 128 + ct * 16 + m] = f_to_bf16(o);
        }
    }
}

// ---------------- GEMM2 (K=128): bf16 A, LN+SiLU -> bf16
__global__ __launch_bounds__(256) void gemm2_ln_mfma(
    const unsigned short* __restrict__ A,
    const unsigned short* __restrict__ w2p,  // [4][8][512] fragment-linear
    const float* __restrict__ bias,
    const float* __restrict__ gam,
    const float* __restrict__ bet,
    unsigned short* __restrict__ Out)
{
    const int t = threadIdx.x;
    const int wv = t >> 6, lane = t & 63;
    const int m = lane & 15, quad = lane >> 4;
    const int row0 = blockIdx.x * 64 + wv * 16;

    f32x4 acc[8] = {};
    const unsigned short* arow = A + (size_t)(row0 + m) * 128 + quad * 8;
    const unsigned short* bb   = w2p + lane * 8;

#pragma unroll
    for (int k0 = 0; k0 < 128; k0 += 32) {
        bf16x8 af = *(const bf16x8*)(arow + k0);
#pragma unroll
        for (int ct = 0; ct < 8; ++ct) {
            bf16x8 bfv = *(const bf16x8*)(bb + (size_t)(((k0 >> 5) * 8 + ct)) * 512);
            acc[ct] = __builtin_amdgcn_mfma_f32_16x16x32_bf16(af, bfv, acc[ct], 0, 0, 0);
        }
    }

    float bbv[8], ggv[8], eev[8];
#pragma unroll
    for (int ct = 0; ct < 8; ++ct) {
        bbv[ct] = bias[ct * 16 + m];
        ggv[ct] = gam[ct * 16 + m];
        eev[ct] = bet[ct * 16 + m];
    }
#pragma unroll
    for (int reg = 0; reg < 4; ++reg) {
        float v[8];
        float s = 0.f, s2 = 0.f;
#pragma unroll
        for (int ct = 0; ct < 8; ++ct) {
            v[ct] = acc[ct][reg] + bbv[ct];
            s += v[ct]; s2 += v[ct] * v[ct];
        }
#pragma unroll
        for (int off = 1; off < 16; off <<= 1) {
            s  += __shfl_xor(s, off, 64);
            s2 += __shfl_xor(s2, off, 64);
        }
        float mean = s * (1.0f / 128.0f);
        float var  = s2 * (1.0f / 128.0f) - mean * mean;
        float rstd = rsqrtf(var + 1e-5f);
        int row = row0 + 4 * quad + reg;
#pragma unroll
        for (int ct = 0; ct < 8; ++ct) {
            float o = silu_f((v[ct] - mean) * rstd * ggv[ct] + eev[ct]);
            Out[(size_t)row * 128 + ct * 16 + m] = f_to_bf16(o);
        }
    }
}

// ---------------- GEMM3: H2b @ w3 + b3, /RESCALE -> bf16 X0p [NE,128,8]
__global__ __launch_bounds__(256) void gemm3_mfma(
    const unsigned short* __restrict__ A,    // [NE,128]
    const unsigned short* __restrict__ w3p,  // [4][7][8][512] fragment-linear
    const float* __restrict__ b3,            // [896]
    unsigned short* __restrict__ X0p)        // [NE,128,8]
{
    const int t = threadIdx.x;
    const int wv = t >> 6, lane = t & 63;
    const int m = lane & 15, quad = lane >> 4;
    const int row0 = blockIdx.x * 16;
    const int c0 = wv * 32;

    f32x4 acc[14] = {};   // index = o*2 + chalf
    const unsigned short* arow = A + (size_t)(row0 + m) * 128 + quad * 8;
    const unsigned short* bb   = w3p + lane * 8;

#pragma unroll
    for (int k0 = 0; k0 < 128; k0 += 32) {
        bf16x8 af = *(const bf16x8*)(arow + k0);
#pragma unroll
        for (int o = 0; o < 7; ++o) {
#pragma unroll
            for (int ch2 = 0; ch2 < 2; ++ch2) {
                bf16x8 bfv = *(const bf16x8*)(bb +
                    (size_t)((((k0 >> 5) * 7 + o) * 8 + (wv * 2 + ch2))) * 512);
                acc[o * 2 + ch2] =
                    __builtin_amdgcn_mfma_f32_16x16x32_bf16(af, bfv, acc[o * 2 + ch2], 0, 0, 0);
            }
        }
    }

    const float inv_res = 1.0f / RESCALE_F;
    float bv[14];
#pragma unroll
    for (int o = 0; o < 7; ++o)
#pragma unroll
        for (int ch2 = 0; ch2 < 2; ++ch2)
            bv[o * 2 + ch2] = b3[o * 128 + c0 + ch2 * 16 + m];

#pragma unroll
    for (int reg = 0; reg < 4; ++reg) {
        int row = row0 + 4 * quad + reg;
#pragma unroll
        for (int ch2 = 0; ch2 < 2; ++ch2) {
            int c = c0 + ch2 * 16 + m;
            union { unsigned short us[8]; uint4 q; } pk;
#pragma unroll
            for (int o = 0; o < 7; ++o)
                pk.us[o] = f_to_bf16((acc[o * 2 + ch2][reg] + bv[o * 2 + ch2]) * inv_res);
            pk.us[7] = 0;   // zero pad: K-pad lane of the rotate MFMA must be 0
            *(uint4*)(X0p + (size_t)row * 1024 + c * 8) = pk.q;
        }
    }
}

// ---------------- counting sort of edges by target node
__global__ __launch_bounds__(256) void hist_kernel(
    const int* __restrict__ edge_index, int* __restrict__ cnt)
{
    int e = blockIdx.x * 256 + threadIdx.x;
    if (e < NE) atomicAdd(&cnt[edge_index[NE + e]], 1);
}

__global__ __launch_bounds__(256) void scan_kernel(
    const int* __restrict__ cnt, int* __restrict__ offs, int* __restrict__ cur)
{
    __shared__ int part[256];
    const int t = threadIdx.x;
    const int base = t * 7;
    int s = 0;
#pragma unroll
    for (int j = 0; j < 7; ++j) {
        int i = base + j;
        if (i < NNODES) s += cnt[i];
    }
    part[t] = s;
    __syncthreads();
    for (int off = 1; off < 256; off <<= 1) {
        int v = (t >= off) ? part[t - off] : 0;
        __syncthreads();
        part[t] += v;
        __syncthreads();
    }
    int run = (t > 0) ? part[t - 1] : 0;
#pragma unroll
    for (int j = 0; j < 7; ++j) {
        int i = base + j;
        if (i < NNODES) {
            offs[i] = run;
            cur[i] = run;
            run += cnt[i];
        }
    }
    if (t == 0) offs[NNODES] = part[255];
}

__global__ __launch_bounds__(256) void scatter_kernel(
    const int* __restrict__ edge_index, int* __restrict__ cur, int* __restrict__ order)
{
    int e = blockIdx.x * 256 + threadIdx.x;
    if (e < NE) {
        int tgt = edge_index[NE + e];
        int pos = atomicAdd(&cur[tgt], 1);
        order[pos] = e;
    }
}

// ---------------- chunk list
__global__ __launch_bounds__(256) void build_chunks(
    const int* __restrict__ offs, int* __restrict__ chunk_cnt,
    int* __restrict__ ch_node, int* __restrict__ ch_beg, int* __restrict__ ch_lm)
{
    int n = blockIdx.x * 256 + threadIdx.x;
    if (n >= NNODES) return;
    int b = offs[n], k = offs[n + 1] - b;
    if (k == 0) return;
    int nc = (k + CH - 1) / CH;
    int base = atomicAdd(chunk_cnt, nc);
    for (int c = 0; c < nc; ++c) {
        ch_node[base + c] = n;
        ch_beg[base + c]  = b + CH * c;
        int l = min(CH, k - CH * c);
        ch_lm[base + c] = l | ((nc > 1) ? 0x10000 : 0);
    }
}

// ---------------- wigner compaction: stream wig coalesced once, emit the 7
// selected columns as bf16 rows of 8 (7+pad), ORDER-POSITION indexed so that
// each rotate chunk's wigner data is one contiguous 22 KB span.
__global__ __launch_bounds__(256) void wig_extract(
    const float* __restrict__ wig,     // [NE,49,29]
    const int* __restrict__ order,     // [NE]
    unsigned short* __restrict__ Wc)   // [NE][49][8] bf16, index = order pos
{
    __shared__ float raw[8 * 1421];    // 45472 B
    __shared__ int eloc[8];

    const int t = threadIdx.x;
    const int p0 = blockIdx.x * 8;
    if (t < 8) eloc[t] = order[p0 + t];
    __syncthreads();

    // stage: 8 groups of 32 lanes; group g streams edge eloc[g]'s 1421 floats
    {
        const int g = t >> 5, l = t & 31;
        const float* src = wig + (size_t)eloc[g] * (NSPH * NALLC);
        float* dst = raw + g * 1421;
#pragma unroll
        for (int it = 0; it < 45; ++it) {
            int i = it * 32 + l;
            if (i < 1421) dst[i] = src[i];
        }
    }
    __syncthreads();

    // compact: 8 edges x 49 rows -> uint4 each, contiguous coalesced store
    uint4* wout = (uint4*)(Wc + (size_t)p0 * WCPE);
    for (int q = t; q < 8 * NSPH; q += 256) {
        int pl = q / NSPH, row = q - pl * NSPH;
        const float* r = raw + pl * 1421 + row * NALLC;
        union { unsigned short us[8]; uint4 v; } pk;
        pk.us[0] = f_to_bf16(r[0]);
        pk.us[1] = f_to_bf16(r[2]);
        pk.us[2] = f_to_bf16(r[6]);
        pk.us[3] = f_to_bf16(r[11]);
        pk.us[4] = f_to_bf16(r[16]);
        pk.us[5] = f_to_bf16(r[21]);
        pk.us[6] = f_to_bf16(r[26]);
        pk.us[7] = 0;
        wout[q] = pk.v;
    }
}

// ---------------- rotate + reduce via MFMA, wigner staged from compact Wc
// (contiguous per chunk) when available; falls back to scattered gather.
__global__ __launch_bounds__(256) void rotate_chunks_mfma(
    const unsigned short* __restrict__ X0p, // [NE,128,8] bf16 (already /RESCALE)
    const float* __restrict__ wig,          // [NE,49,29] (fallback only)
    const unsigned short* __restrict__ Wc,  // [NE][49][8] order-indexed
    const int use_wc,
    const int* __restrict__ order,
    const int* __restrict__ chunk_cnt,
    const int* __restrict__ ch_node,
    const int* __restrict__ ch_beg,
    const int* __restrict__ ch_lm,
    float* __restrict__ out)                // [1600,49,128] (pre-zeroed)
{
    __shared__ unsigned short Ws[CH][64][8];   // [slot][row(49+15)][o(7+1)] 28672 B
    __shared__ int es[CH];

    const int b = blockIdx.x;
    if (b >= chunk_cnt[0]) return;
    const int node = ch_node[b];
    const int beg  = ch_beg[b];
    const int lm   = ch_lm[b];
    const int len  = lm & 0xFFFF;
    const int multi = lm >> 16;

    const int t = threadIdx.x;
    const int wv = t >> 6, lane = t & 63;
    const int m = lane & 15, quad = lane >> 4;

    if (t < CH) es[t] = order[beg + ((t < len) ? t : 0)];

    if (use_wc) {
        // contiguous coalesced staging: len*49 uint4 from Wc[beg..beg+len)
        const uint4* wsrc = (const uint4*)(Wc + (size_t)beg * WCPE);
        const int nval = len * NSPH;
        for (int q = t; q < CH * NSPH; q += 256) {      // 1372
            int slot = q / NSPH, row = q - slot * NSPH;
            uint4 v = make_uint4(0u, 0u, 0u, 0u);
            if (q < nval) v = wsrc[q];
            *(uint4*)&Ws[slot][row][0] = v;
        }
        for (int q = t; q < CH * 15; q += 256) {        // zero pad rows 49..63
            int slot = q / 15, row = 49 + (q - (q / 15) * 15);
            *(uint4*)&Ws[slot][row][0] = make_uint4(0u, 0u, 0u, 0u);
        }
    } else {
        const int slot8 = t >> 3;
        const int lane8 = t & 7;
        if (slot8 < CH) {
            const int e = (slot8 < len) ? order[beg + slot8] : -1;
            const float* wsrc = wig + (size_t)e * (NSPH * NALLC);
#pragma unroll
            for (int j = 0; j < 49; ++j) {
                int idx = j * 8 + lane8;
                int i = idx >> 3, o = idx & 7;
                float v = 0.f;
                if (e >= 0 && o < 7) {
                    int col = (o < 2) ? (2 * o) : (5 * o - 4);
                    v = wsrc[i * NALLC + col];
                }
                Ws[slot8][i][o] = f_to_bf16(v);
            }
#pragma unroll
            for (int j = 0; j < 15; ++j)
                Ws[slot8][49 + j][lane8] = 0;
        }
    }
    __syncthreads();

    // ---- MFMA: wave wv owns M-tile rows wv*16..+15, all 8 N-tiles
    f32x4 acc[8] = {};
    for (int g = 0; g < 7; ++g) {
        const int e = es[g * 4 + quad];
        const unsigned short* xb = X0p + (size_t)e * 1024 + m * 8;
        bf16x8 aq = *(const bf16x8*)&Ws[g * 4 + quad][wv * 16 + m][0];
#pragma unroll
        for (int nt = 0; nt < 8; ++nt) {
            bf16x8 bq = *(const bf16x8*)(xb + nt * 128);
            acc[nt] = __builtin_amdgcn_mfma_f32_16x16x32_bf16(aq, bq, acc[nt], 0, 0, 0);
        }
    }

    // ---- C write: D row = wv*16 + quad*4 + reg (sph), col = nt*16 + m
    float* op = out + (size_t)node * (NSPH * CCH);
    const int r0 = wv * 16 + quad * 4;
    if (multi) {
#pragma unroll
        for (int nt = 0; nt < 8; ++nt) {
            int c = nt * 16 + m;
#pragma unroll
            for (int reg = 0; reg < 4; ++reg) {
                int sph = r0 + reg;
                if (sph < NSPH) atomicAdd(&op[sph * CCH + c], acc[nt][reg]);
            }
        }
    } else {
#pragma unroll
        for (int nt = 0; nt < 8; ++nt) {
            int c = nt * 16 + m;
#pragma unroll
            for (int reg = 0; reg < 4; ++reg) {
                int sph = r0 + reg;
                if (sph < NSPH) op[sph * CCH + c] = acc[nt][reg];
            }
        }
    }
}

extern "C" void kernel_launch(void* const* d_in, const int* in_sizes, int n_in,
                              void* d_out, int out_size, void* d_ws, size_t ws_size,
                              hipStream_t stream) {
    const int*   atomic_numbers = (const int*)d_in[0];
    const float* edge_distance  = (const float*)d_in[1];
    const int*   edge_index     = (const int*)d_in[2];
    const float* src_table      = (const float*)d_in[3];
    const float* tgt_table      = (const float*)d_in[4];
    const float* w1  = (const float*)d_in[5];
    const float* b1  = (const float*)d_in[6];
    const float* g1  = (const float*)d_in[7];
    const float* be1 = (const float*)d_in[8];
    const float* w2  = (const float*)d_in[9];
    const float* b2  = (const float*)d_in[10];
    const float* g2  = (const float*)d_in[11];
    const float* be2 = (const float*)d_in[12];
    const float* w3  = (const float*)d_in[13];
    const float* b3  = (const float*)d_in[14];
    // d_in[15] = to_m (fixed permutation, hard-coded)
    const float* wig = (const float*)d_in[16];

    char* ws = (char*)d_ws;
    unsigned short* H1b = (unsigned short*)(ws);                 //  8.192 MB
    unsigned short* H2b = (unsigned short*)(ws + 8192000);       //  8.192 MB
    unsigned short* X0p = (unsigned short*)(ws + 16384000);      // 65.536 MB
    unsigned short* w1p = (unsigned short*)(ws + 81920000);      // 196608 B
    unsigned short* w2p = (unsigned short*)(ws + 82116608);      // 32768 B
    unsigned short* w3p = (unsigned short*)(ws + 82149376);      // 229376 B
    int* ints      = (int*)(ws + 82378752);
    int* cnt       = ints;                   // [1600]
    int* chunk_cnt = cnt + NNODES;           // [1]
    int* offs      = chunk_cnt + 1;          // [1601]
    int* cur       = offs + NNODES + 1;      // [1600]
    int* order     = cur + NNODES;           // [32000]
    int* ch_node   = order + NE;             // [MAXCH]
    int* ch_beg    = ch_node + MAXCH;        // [MAXCH]
    int* ch_lm     = ch_beg + MAXCH;         // [MAXCH]
    // compact wigner beyond the proven-safe 90.1 MB watermark — guarded
    const int use_wc = (ws_size >= WC_OFF + WC_BYTES) ? 1 : 0;
    unsigned short* Wc = (unsigned short*)(ws + WC_OFF);         // 25.088 MB

    hipMemsetAsync(cnt, 0, (NNODES + 1) * sizeof(int), stream);
    hipMemsetAsync(d_out, 0, (size_t)out_size * sizeof(float), stream);

    // bucket + chunk build
    hist_kernel<<<(NE + 255) / 256, 256, 0, stream>>>(edge_index, cnt);
    scan_kernel<<<1, 256, 0, stream>>>(cnt, offs, cur);
    scatter_kernel<<<(NE + 255) / 256, 256, 0, stream>>>(edge_index, cur, order);
    build_chunks<<<(NNODES + 255) / 256, 256, 0, stream>>>(
        offs, chunk_cnt, ch_node, ch_beg, ch_lm);

    // wigner compaction (needs order); overlaps nothing live
    if (use_wc)
        wig_extract<<<NE / 8, 256, 0, stream>>>(wig, order, Wc);

    // weights prepack + MLP (bf16 MFMA)
    prepack_w<<<(229376 + 255) / 256, 256, 0, stream>>>(w1, w2, w3, w1p, w2p, w3p);
    gemm1_ln_mfma<<<NE / 64, 256, 0, stream>>>(
        edge_distance, edge_index, atomic_numbers, src_table, tgt_table,
        w1p, b1, g1, be1, H1b);
    gemm2_ln_mfma<<<NE / 64, 256, 0, stream>>>(H1b, w2p, b2, g2, be2, H2b);
    gemm3_mfma<<<NE / 16, 256, 0, stream>>>(H2b, w3p, b3, X0p);

    // rotate + reduce (MFMA)
    rotate_chunks_mfma<<<MAXCH, 256, 0, stream>>>(
        X0p, wig, Wc, use_wc, order, chunk_cnt, ch_node, ch_beg, ch_lm,
        (float*)d_out);
}

// Round 7
// 456.601 us; speedup vs baseline: 1.0187x; 1.0187x over previous
//
#include <hip/hip_runtime.h>
#include <hip/hip_bf16.h>

#define NE 32000
#define NNODES 1600
#define CCH 128
#define M0C 7
#define NSPH 49
#define NALLC 29
#define BASIS 512
#define DIN 768
#define HID 128
#define RESCALE_F 23.395238876342773f
#define CH 28                      // edges per rotate chunk
#define MAXCH (NE / CH + NNODES)   // 2743 upper bound on chunk count
#define WCROW 8                    // shorts per compact wigner row (7 + pad)
#define WCPE (NSPH * WCROW)        // 392 shorts per edge in Wc
#define WC_OFF 82558976ull
#define WC_BYTES (2ull * NE * WCPE)

typedef __bf16 bf16x8 __attribute__((ext_vector_type(8)));
typedef __bf16 bf16x2 __attribute__((ext_vector_type(2)));
typedef float  f32x4  __attribute__((ext_vector_type(4)));

__device__ __forceinline__ unsigned short f_to_bf16(float f) {
    unsigned int u = __float_as_uint(f);
    unsigned int r = (u + 0x7FFFu + ((u >> 16) & 1u)) >> 16;
    return (unsigned short)r;
}
__device__ __forceinline__ float silu_f(float x) {
    return x / (1.0f + __expf(-x));
}

// ---------------- prepack weights: FRAGMENT-LINEAR layout (1 KB contiguous
// per (kstep,tile) wave-fragment; lane L's 8 values at [lane*8..lane*8+8)).
__global__ __launch_bounds__(256) void prepack_w(
    const float* __restrict__ w1, const float* __restrict__ w2, const float* __restrict__ w3,
    unsigned short* __restrict__ w1p,  // [24][8][512]
    unsigned short* __restrict__ w2p,  // [4][8][512]
    unsigned short* __restrict__ w3p)  // [4][7][8][512]
{
    int idx = blockIdx.x * 256 + threadIdx.x;
    if (idx < 98304) {                       // w1p: 24*8*512
        int kstep = idx >> 12;
        int ct    = (idx >> 9) & 7;
        int li    = idx & 511;
        int lane = li >> 3, j = li & 7;
        int m = lane & 15, quad = lane >> 4;
        int k = kstep * 32 + quad * 8 + j;
        int n = ct * 16 + m;
        w1p[idx] = f_to_bf16(w1[(size_t)k * 128 + n]);
    } else if (idx < 114688) {               // w2p: 4*8*512
        int j2 = idx - 98304;
        int kstep = j2 >> 12;
        int ct    = (j2 >> 9) & 7;
        int li    = j2 & 511;
        int lane = li >> 3, j = li & 7;
        int m = lane & 15, quad = lane >> 4;
        int k = kstep * 32 + quad * 8 + j;
        int n = ct * 16 + m;
        w2p[j2] = f_to_bf16(w2[(size_t)k * 128 + n]);
    } else if (idx < 229376) {               // w3p: 4*7*8*512
        int j3 = idx - 114688;
        int kstep = j3 / 28672;
        int r     = j3 - kstep * 28672;
        int o     = r >> 12;
        int ctile = (r >> 9) & 7;
        int li    = r & 511;
        int lane = li >> 3, j = li & 7;
        int m = lane & 15, quad = lane >> 4;
        int k = kstep * 32 + quad * 8 + j;
        int n = o * 128 + ctile * 16 + m;
        w3p[j3] = f_to_bf16(w3[(size_t)k * 896 + n]);
    }
}

// ---------------- GEMM1 (R5 version, direct loads): A = [dist|src|tgt] fp32,
// cvt in-reg. 64 rows/block, 4 waves x 16 rows, MFMA 16x16x32, LN+SiLU.
__global__ __launch_bounds__(256) void gemm1_ln_mfma(
    const float* __restrict__ dist,         // [NE,512]
    const int* __restrict__ edge_index,     // [2,NE]
    const int* __restrict__ atomic_numbers, // [NNODES]
    const float* __restrict__ src_table,    // [90,128]
    const float* __restrict__ tgt_table,    // [90,128]
    const unsigned short* __restrict__ w1p, // [24][8][512] fragment-linear
    const float* __restrict__ bias,
    const float* __restrict__ gam,
    const float* __restrict__ bet,
    unsigned short* __restrict__ Out)       // [NE,128] bf16
{
    const int t = threadIdx.x;
    const int wv = t >> 6, lane = t & 63;
    const int m = lane & 15, quad = lane >> 4;
    const int row0 = blockIdx.x * 64 + wv * 16;
    const int row = row0 + m;

    const int sid  = atomic_numbers[edge_index[row]];
    const int tid2 = atomic_numbers[edge_index[NE + row]];
    const float* a0 = dist + (size_t)row * 512 + quad * 8;
    const float* a1 = src_table + sid * 128 + quad * 8;
    const float* a2 = tgt_table + tid2 * 128 + quad * 8;
    const unsigned short* bb = w1p + lane * 8;

    f32x4 acc[8] = {};

#pragma unroll
    for (int k0 = 0; k0 < 768; k0 += 32) {
        const float* ap = (k0 < 512) ? (a0 + k0)
                        : (k0 < 640) ? (a1 + (k0 - 512))
                                     : (a2 + (k0 - 640));
        float4 va = *(const float4*)ap;
        float4 vb = *(const float4*)(ap + 4);
        bf16x8 af;
        af[0] = (__bf16)va.x; af[1] = (__bf16)va.y;
        af[2] = (__bf16)va.z; af[3] = (__bf16)va.w;
        af[4] = (__bf16)vb.x; af[5] = (__bf16)vb.y;
        af[6] = (__bf16)vb.z; af[7] = (__bf16)vb.w;
#pragma unroll
        for (int ct = 0; ct < 8; ++ct) {
            bf16x8 bfv = *(const bf16x8*)(bb + (size_t)(((k0 >> 5) * 8 + ct)) * 512);
            acc[ct] = __builtin_amdgcn_mfma_f32_16x16x32_bf16(af, bfv, acc[ct], 0, 0, 0);
        }
    }

    float bbv[8], ggv[8], eev[8];
#pragma unroll
    for (int ct = 0; ct < 8; ++ct) {
        bbv[ct] = bias[ct * 16 + m];
        ggv[ct] = gam[ct * 16 + m];
        eev[ct] = bet[ct * 16 + m];
    }
#pragma unroll
    for (int reg = 0; reg < 4; ++reg) {
        float v[8];
        float s = 0.f, s2 = 0.f;
#pragma unroll
        for (int ct = 0; ct < 8; ++ct) {
            v[ct] = acc[ct][reg] + bbv[ct];
            s += v[ct]; s2 += v[ct] * v[ct];
        }
#pragma unroll
        for (int off = 1; off < 16; off <<= 1) {
            s  += __shfl_xor(s, off, 64);
            s2 += __shfl_xor(s2, off, 64);
        }
        float mean = s * (1.0f / 128.0f);
        float var  = s2 * (1.0f / 128.0f) - mean * mean;
        float rstd = rsqrtf(var + 1e-5f);
        int orow = row0 + 4 * quad + reg;
#pragma unroll
        for (int ct = 0; ct < 8; ++ct) {
            float o = silu_f((v[ct] - mean) * rstd * ggv[ct] + eev[ct]);
            Out[(size_t)orow * 128 + ct * 16 + m] = f_to_bf16(o);
        }
    }
}

// ---------------- GEMM2 (K=128): bf16 A, LN+SiLU -> bf16
__global__ __launch_bounds__(256) void gemm2_ln_mfma(
    const unsigned short* __restrict__ A,
    const unsigned short* __restrict__ w2p,  // [4][8][512] fragment-linear
    const float* __restrict__ bias,
    const float* __restrict__ gam,
    const float* __restrict__ bet,
    unsigned short* __restrict__ Out)
{
    const int t = threadIdx.x;
    const int wv = t >> 6, lane = t & 63;
    const int m = lane & 15, quad = lane >> 4;
    const int row0 = blockIdx.x * 64 + wv * 16;

    f32x4 acc[8] = {};
    const unsigned short* arow = A + (size_t)(row0 + m) * 128 + quad * 8;
    const unsigned short* bb   = w2p + lane * 8;

#pragma unroll
    for (int k0 = 0; k0 < 128; k0 += 32) {
        bf16x8 af = *(const bf16x8*)(arow + k0);
#pragma unroll
        for (int ct = 0; ct < 8; ++ct) {
            bf16x8 bfv = *(const bf16x8*)(bb + (size_t)(((k0 >> 5) * 8 + ct)) * 512);
            acc[ct] = __builtin_amdgcn_mfma_f32_16x16x32_bf16(af, bfv, acc[ct], 0, 0, 0);
        }
    }

    float bbv[8], ggv[8], eev[8];
#pragma unroll
    for (int ct = 0; ct < 8; ++ct) {
        bbv[ct] = bias[ct * 16 + m];
        ggv[ct] = gam[ct * 16 + m];
        eev[ct] = bet[ct * 16 + m];
    }
#pragma unroll
    for (int reg = 0; reg < 4; ++reg) {
        float v[8];
        float s = 0.f, s2 = 0.f;
#pragma unroll
        for (int ct = 0; ct < 8; ++ct) {
            v[ct] = acc[ct][reg] + bbv[ct];
            s += v[ct]; s2 += v[ct] * v[ct];
        }
#pragma unroll
        for (int off = 1; off < 16; off <<= 1) {
            s  += __shfl_xor(s, off, 64);
            s2 += __shfl_xor(s2, off, 64);
        }
        float mean = s * (1.0f / 128.0f);
        float var  = s2 * (1.0f / 128.0f) - mean * mean;
        float rstd = rsqrtf(var + 1e-5f);
        int row = row0 + 4 * quad + reg;
#pragma unroll
        for (int ct = 0; ct < 8; ++ct) {
            float o = silu_f((v[ct] - mean) * rstd * ggv[ct] + eev[ct]);
            Out[(size_t)row * 128 + ct * 16 + m] = f_to_bf16(o);
        }
    }
}

// ---------------- GEMM3: H2b @ w3 + b3, /RESCALE -> bf16 X0p [NE,128,8]
__global__ __launch_bounds__(256) void gemm3_mfma(
    const unsigned short* __restrict__ A,    // [NE,128]
    const unsigned short* __restrict__ w3p,  // [4][7][8][512] fragment-linear
    const float* __restrict__ b3,            // [896]
    unsigned short* __restrict__ X0p)        // [NE,128,8]
{
    const int t = threadIdx.x;
    const int wv = t >> 6, lane = t & 63;
    const int m = lane & 15, quad = lane >> 4;
    const int row0 = blockIdx.x * 16;
    const int c0 = wv * 32;

    f32x4 acc[14] = {};   // index = o*2 + chalf
    const unsigned short* arow = A + (size_t)(row0 + m) * 128 + quad * 8;
    const unsigned short* bb   = w3p + lane * 8;

#pragma unroll
    for (int k0 = 0; k0 < 128; k0 += 32) {
        bf16x8 af = *(const bf16x8*)(arow + k0);
#pragma unroll
        for (int o = 0; o < 7; ++o) {
#pragma unroll
            for (int ch2 = 0; ch2 < 2; ++ch2) {
                bf16x8 bfv = *(const bf16x8*)(bb +
                    (size_t)((((k0 >> 5) * 7 + o) * 8 + (wv * 2 + ch2))) * 512);
                acc[o * 2 + ch2] =
                    __builtin_amdgcn_mfma_f32_16x16x32_bf16(af, bfv, acc[o * 2 + ch2], 0, 0, 0);
            }
        }
    }

    const float inv_res = 1.0f / RESCALE_F;
    float bv[14];
#pragma unroll
    for (int o = 0; o < 7; ++o)
#pragma unroll
        for (int ch2 = 0; ch2 < 2; ++ch2)
            bv[o * 2 + ch2] = b3[o * 128 + c0 + ch2 * 16 + m];

#pragma unroll
    for (int reg = 0; reg < 4; ++reg) {
        int row = row0 + 4 * quad + reg;
#pragma unroll
        for (int ch2 = 0; ch2 < 2; ++ch2) {
            int c = c0 + ch2 * 16 + m;
            union { unsigned short us[8]; uint4 q; } pk;
#pragma unroll
            for (int o = 0; o < 7; ++o)
                pk.us[o] = f_to_bf16((acc[o * 2 + ch2][reg] + bv[o * 2 + ch2]) * inv_res);
            pk.us[7] = 0;   // zero pad: K-pad lane of the rotate MFMA must be 0
            *(uint4*)(X0p + (size_t)row * 1024 + c * 8) = pk.q;
        }
    }
}

// ---------------- counting sort of edges by target node
__global__ __launch_bounds__(256) void hist_kernel(
    const int* __restrict__ edge_index, int* __restrict__ cnt)
{
    int e = blockIdx.x * 256 + threadIdx.x;
    if (e < NE) atomicAdd(&cnt[edge_index[NE + e]], 1);
}

__global__ __launch_bounds__(256) void scan_kernel(
    const int* __restrict__ cnt, int* __restrict__ offs, int* __restrict__ cur)
{
    __shared__ int part[256];
    const int t = threadIdx.x;
    const int base = t * 7;
    int s = 0;
#pragma unroll
    for (int j = 0; j < 7; ++j) {
        int i = base + j;
        if (i < NNODES) s += cnt[i];
    }
    part[t] = s;
    __syncthreads();
    for (int off = 1; off < 256; off <<= 1) {
        int v = (t >= off) ? part[t - off] : 0;
        __syncthreads();
        part[t] += v;
        __syncthreads();
    }
    int run = (t > 0) ? part[t - 1] : 0;
#pragma unroll
    for (int j = 0; j < 7; ++j) {
        int i = base + j;
        if (i < NNODES) {
            offs[i] = run;
            cur[i] = run;
            run += cnt[i];
        }
    }
    if (t == 0) offs[NNODES] = part[255];
}

__global__ __launch_bounds__(256) void scatter_kernel(
    const int* __restrict__ edge_index, int* __restrict__ cur, int* __restrict__ order)
{
    int e = blockIdx.x * 256 + threadIdx.x;
    if (e < NE) {
        int tgt = edge_index[NE + e];
        int pos = atomicAdd(&cur[tgt], 1);
        order[pos] = e;
    }
}

// ---------------- chunk list
__global__ __launch_bounds__(256) void build_chunks(
    const int* __restrict__ offs, int* __restrict__ chunk_cnt,
    int* __restrict__ ch_node, int* __restrict__ ch_beg, int* __restrict__ ch_lm)
{
    int n = blockIdx.x * 256 + threadIdx.x;
    if (n >= NNODES) return;
    int b = offs[n], k = offs[n + 1] - b;
    if (k == 0) return;
    int nc = (k + CH - 1) / CH;
    int base = atomicAdd(chunk_cnt, nc);
    for (int c = 0; c < nc; ++c) {
        ch_node[base + c] = n;
        ch_beg[base + c]  = b + CH * c;
        int l = min(CH, k - CH * c);
        ch_lm[base + c] = l | ((nc > 1) ? 0x10000 : 0);
    }
}

// ---------------- wigner compaction: stream wig coalesced once, emit the 7
// selected columns as bf16 rows of 8 (7+pad), ORDER-POSITION indexed so that
// each rotate chunk's wigner data is one contiguous span.
__global__ __launch_bounds__(256) void wig_extract(
    const float* __restrict__ wig,     // [NE,49,29]
    const int* __restrict__ order,     // [NE]
    unsigned short* __restrict__ Wc)   // [NE][49][8] bf16, index = order pos
{
    __shared__ float raw[8 * 1421];    // 45472 B
    __shared__ int eloc[8];

    const int t = threadIdx.x;
    const int p0 = blockIdx.x * 8;
    if (t < 8) eloc[t] = order[p0 + t];
    __syncthreads();

    // stage: 8 groups of 32 lanes; group g streams edge eloc[g]'s 1421 floats
    {
        const int g = t >> 5, l = t & 31;
        const float* src = wig + (size_t)eloc[g] * (NSPH * NALLC);
        float* dst = raw + g * 1421;
#pragma unroll
        for (int it = 0; it < 45; ++it) {
            int i = it * 32 + l;
            if (i < 1421) dst[i] = src[i];
        }
    }
    __syncthreads();

    // compact: 8 edges x 49 rows -> uint4 each, contiguous coalesced store
    uint4* wout = (uint4*)(Wc + (size_t)p0 * WCPE);
    for (int q = t; q < 8 * NSPH; q += 256) {
        int pl = q / NSPH, row = q - pl * NSPH;
        const float* r = raw + pl * 1421 + row * NALLC;
        union { unsigned short us[8]; uint4 v; } pk;
        pk.us[0] = f_to_bf16(r[0]);
        pk.us[1] = f_to_bf16(r[2]);
        pk.us[2] = f_to_bf16(r[6]);
        pk.us[3] = f_to_bf16(r[11]);
        pk.us[4] = f_to_bf16(r[16]);
        pk.us[5] = f_to_bf16(r[21]);
        pk.us[6] = f_to_bf16(r[26]);
        pk.us[7] = 0;
        wout[q] = pk.v;
    }
}

// ---------------- rotate + reduce via MFMA, LEN-AWARE: only ceil(len/4) of
// the 7 K-groups are staged/loaded/MFMA'd (chunks average 11.7 edges of 28 —
// the fixed-trip version wasted ~58% of MFMA, staging and X0p B-loads on
// zero A-rows).
__global__ __launch_bounds__(256) void rotate_chunks_mfma(
    const unsigned short* __restrict__ X0p, // [NE,128,8] bf16 (already /RESCALE)
    const float* __restrict__ wig,          // [NE,49,29] (fallback only)
    const unsigned short* __restrict__ Wc,  // [NE][49][8] order-indexed
    const int use_wc,
    const int* __restrict__ order,
    const int* __restrict__ chunk_cnt,
    const int* __restrict__ ch_node,
    const int* __restrict__ ch_beg,
    const int* __restrict__ ch_lm,
    float* __restrict__ out)                // [1600,49,128] (pre-zeroed)
{
    __shared__ unsigned short Ws[CH][64][8];   // [slot][row(49+15)][o(7+1)] 28672 B
    __shared__ int es[CH];

    const int b = blockIdx.x;
    if (b >= chunk_cnt[0]) return;
    const int node = ch_node[b];
    const int beg  = ch_beg[b];
    const int lm   = ch_lm[b];
    const int len  = lm & 0xFFFF;
    const int multi = lm >> 16;
    const int gmax  = (len + 3) >> 2;     // active K-groups (1..7)
    const int nslot = gmax * 4;           // staged slots (multiple of 4)

    const int t = threadIdx.x;
    const int wv = t >> 6, lane = t & 63;
    const int m = lane & 15, quad = lane >> 4;

    if (t < CH) es[t] = order[beg + ((t < len) ? t : 0)];

    if (use_wc) {
        // contiguous coalesced staging of the active slots only
        const uint4* wsrc = (const uint4*)(Wc + (size_t)beg * WCPE);
        const int nval = len * NSPH;
        for (int q = t; q < nslot * NSPH; q += 256) {
            int slot = q / NSPH, row = q - slot * NSPH;
            uint4 v = make_uint4(0u, 0u, 0u, 0u);
            if (q < nval) v = wsrc[q];
            *(uint4*)&Ws[slot][row][0] = v;
        }
        for (int q = t; q < nslot * 15; q += 256) {     // zero pad rows 49..63
            int slot = q / 15, row = 49 + (q - (q / 15) * 15);
            *(uint4*)&Ws[slot][row][0] = make_uint4(0u, 0u, 0u, 0u);
        }
    } else {
        const int slot8 = t >> 3;
        const int lane8 = t & 7;
        if (slot8 < nslot) {
            const int e = (slot8 < len) ? order[beg + slot8] : -1;
            const float* wsrc = wig + (size_t)e * (NSPH * NALLC);
#pragma unroll
            for (int j = 0; j < 49; ++j) {
                int idx = j * 8 + lane8;
                int i = idx >> 3, o = idx & 7;
                float v = 0.f;
                if (e >= 0 && o < 7) {
                    int col = (o < 2) ? (2 * o) : (5 * o - 4);
                    v = wsrc[i * NALLC + col];
                }
                Ws[slot8][i][o] = f_to_bf16(v);
            }
#pragma unroll
            for (int j = 0; j < 15; ++j)
                Ws[slot8][49 + j][lane8] = 0;
        }
    }
    __syncthreads();

    // ---- MFMA: wave wv owns M-tile rows wv*16..+15, all 8 N-tiles
    f32x4 acc[8] = {};
    for (int g = 0; g < gmax; ++g) {
        const int e = es[g * 4 + quad];
        const unsigned short* xb = X0p + (size_t)e * 1024 + m * 8;
        bf16x8 aq = *(const bf16x8*)&Ws[g * 4 + quad][wv * 16 + m][0];
#pragma unroll
        for (int nt = 0; nt < 8; ++nt) {
            bf16x8 bq = *(const bf16x8*)(xb + nt * 128);
            acc[nt] = __builtin_amdgcn_mfma_f32_16x16x32_bf16(aq, bq, acc[nt], 0, 0, 0);
        }
    }

    // ---- C write: D row = wv*16 + quad*4 + reg (sph), col = nt*16 + m
    float* op = out + (size_t)node * (NSPH * CCH);
    const int r0 = wv * 16 + quad * 4;
    if (multi) {
#pragma unroll
        for (int nt = 0; nt < 8; ++nt) {
            int c = nt * 16 + m;
#pragma unroll
            for (int reg = 0; reg < 4; ++reg) {
                int sph = r0 + reg;
                if (sph < NSPH) atomicAdd(&op[sph * CCH + c], acc[nt][reg]);
            }
        }
    } else {
#pragma unroll
        for (int nt = 0; nt < 8; ++nt) {
            int c = nt * 16 + m;
#pragma unroll
            for (int reg = 0; reg < 4; ++reg) {
                int sph = r0 + reg;
                if (sph < NSPH) op[sph * CCH + c] = acc[nt][reg];
            }
        }
    }
}

extern "C" void kernel_launch(void* const* d_in, const int* in_sizes, int n_in,
                              void* d_out, int out_size, void* d_ws, size_t ws_size,
                              hipStream_t stream) {
    const int*   atomic_numbers = (const int*)d_in[0];
    const float* edge_distance  = (const float*)d_in[1];
    const int*   edge_index     = (const int*)d_in[2];
    const float* src_table      = (const float*)d_in[3];
    const float* tgt_table      = (const float*)d_in[4];
    const float* w1  = (const float*)d_in[5];
    const float* b1  = (const float*)d_in[6];
    const float* g1  = (const float*)d_in[7];
    const float* be1 = (const float*)d_in[8];
    const float* w2  = (const float*)d_in[9];
    const float* b2  = (const float*)d_in[10];
    const float* g2  = (const float*)d_in[11];
    const float* be2 = (const float*)d_in[12];
    const float* w3  = (const float*)d_in[13];
    const float* b3  = (const float*)d_in[14];
    // d_in[15] = to_m (fixed permutation, hard-coded)
    const float* wig = (const float*)d_in[16];

    char* ws = (char*)d_ws;
    unsigned short* H1b = (unsigned short*)(ws);                 //  8.192 MB
    unsigned short* H2b = (unsigned short*)(ws + 8192000);       //  8.192 MB
    unsigned short* X0p = (unsigned short*)(ws + 16384000);      // 65.536 MB
    unsigned short* w1p = (unsigned short*)(ws + 81920000);      // 196608 B
    unsigned short* w2p = (unsigned short*)(ws + 82116608);      // 32768 B
    unsigned short* w3p = (unsigned short*)(ws + 82149376);      // 229376 B
    int* ints      = (int*)(ws + 82378752);
    int* cnt       = ints;                   // [1600]
    int* chunk_cnt = cnt + NNODES;           // [1]
    int* offs      = chunk_cnt + 1;          // [1601]
    int* cur       = offs + NNODES + 1;      // [1600]
    int* order     = cur + NNODES;           // [32000]
    int* ch_node   = order + NE;             // [MAXCH]
    int* ch_beg    = ch_node + MAXCH;        // [MAXCH]
    int* ch_lm     = ch_beg + MAXCH;         // [MAXCH]
    // compact wigner beyond the proven-safe watermark — guarded
    const int use_wc = (ws_size >= WC_OFF + WC_BYTES) ? 1 : 0;
    unsigned short* Wc = (unsigned short*)(ws + WC_OFF);         // 25.088 MB

    hipMemsetAsync(cnt, 0, (NNODES + 1) * sizeof(int), stream);
    hipMemsetAsync(d_out, 0, (size_t)out_size * sizeof(float), stream);

    // bucket + chunk build
    hist_kernel<<<(NE + 255) / 256, 256, 0, stream>>>(edge_index, cnt);
    scan_kernel<<<1, 256, 0, stream>>>(cnt, offs, cur);
    scatter_kernel<<<(NE + 255) / 256, 256, 0, stream>>>(edge_index, cur, order);
    build_chunks<<<(NNODES + 255) / 256, 256, 0, stream>>>(
        offs, chunk_cnt, ch_node, ch_beg, ch_lm);

    // wigner compaction (needs order)
    if (use_wc)
        wig_extract<<<NE / 8, 256, 0, stream>>>(wig, order, Wc);

    // weights prepack + MLP (bf16 MFMA)
    prepack_w<<<(229376 + 255) / 256, 256, 0, stream>>>(w1, w2, w3, w1p, w2p, w3p);
    gemm1_ln_mfma<<<NE / 64, 256, 0, stream>>>(
        edge_distance, edge_index, atomic_numbers, src_table, tgt_table,
        w1p, b1, g1, be1, H1b);
    gemm2_ln_mfma<<<NE / 64, 256, 0, stream>>>(H1b, w2p, b2, g2, be2, H2b);
    gemm3_mfma<<<NE / 16, 256, 0, stream>>>(H2b, w3p, b3, X0p);

    // rotate + reduce (MFMA, len-aware)
    rotate_chunks_mfma<<<MAXCH, 256, 0, stream>>>(
        X0p, wig, Wc, use_wc, order, chunk_cnt, ch_node, ch_beg, ch_lm,
        (float*)d_out);
}